// Round 1
// baseline (1930.264 us; speedup 1.0000x reference)
//
#include <hip/hip_runtime.h>

#define KN 8192      // num embeddings
#define DD 256       // embedding dim
#define HW 1024      // H*W
#define NP 32768     // total pixels (B*H*W)
#define TPX 64       // pixels per block (argmin)
#define TKK 128      // k-tile
#define DCH 32       // d-chunk

// ---------------- kernel 1: e2[k] = sum_d e[d,k]^2 ----------------
__global__ void enorm_kernel(const float* __restrict__ e, float* __restrict__ e2) {
    int k = blockIdx.x * blockDim.x + threadIdx.x;
    float acc = 0.f;
#pragma unroll 8
    for (int d = 0; d < DD; ++d) {
        float v = e[(size_t)d * KN + k];   // coalesced: consecutive k per lane
        acc = fmaf(v, v, acc);
    }
    e2[k] = acc;
}

// ---------------- kernel 2: argmin over K of (e2[k] - 2*z.e_k) ----------------
__device__ __forceinline__ void merge_min(float v, int k, float& bv, int& bi) {
    if (v < bv || (v == bv && k < bi)) { bv = v; bi = k; }
}

__launch_bounds__(256, 2)
__global__ void argmin_kernel(const float* __restrict__ z,
                              const float* __restrict__ e,
                              const float* __restrict__ e2,
                              int* __restrict__ out_idx) {
    __shared__ float zt[DD * TPX];    // 64 KB: zt[d*64+p]
    __shared__ float et[DCH * TKK];   // 16 KB: et[di*128+kk]; reused for reduction

    const int t  = threadIdx.x;
    const int tx = t & 15;            // k-group
    const int ty = t >> 4;            // pixel-group
    const int n0 = blockIdx.x * TPX;  // 64 pixels, all within one batch image
    const float* zb = z + (size_t)(n0 >> 10) * (DD * HW) + (n0 & (HW - 1));

    // stage z tile once: zt[d*64+p] = z[b, d, p0+p]
    for (int i = t; i < DD * TPX / 4; i += 256) {
        int fi = i * 4;
        int d = fi >> 6, p = fi & 63;
        *(float4*)(zt + fi) = *(const float4*)(zb + (size_t)d * HW + p);
    }

    float bestv[4];
    int   besti[4];
#pragma unroll
    for (int i = 0; i < 4; ++i) { bestv[i] = 3.4e38f; besti[i] = 0; }

    for (int k0 = 0; k0 < KN; k0 += TKK) {
        float acc[4][8];
#pragma unroll
        for (int i = 0; i < 4; ++i)
#pragma unroll
            for (int j = 0; j < 8; ++j) acc[i][j] = 0.f;

        for (int d0 = 0; d0 < DD; d0 += DCH) {
            __syncthreads();   // protect et from previous chunk's readers
#pragma unroll
            for (int i = 0; i < (DCH * TKK / 4) / 256; ++i) {   // 4 float4 per thread
                int q  = (t + i * 256) * 4;
                int di = q >> 7, kk = q & 127;
                *(float4*)(et + q) =
                    *(const float4*)(e + (size_t)(d0 + di) * KN + k0 + kk);
            }
            __syncthreads();

#pragma unroll 8
            for (int di = 0; di < DCH; ++di) {
                float4 zv = *(const float4*)(zt + (d0 + di) * TPX + ty * 4);
                float4 ea = *(const float4*)(et + di * TKK + tx * 4);
                float4 eb = *(const float4*)(et + di * TKK + 64 + tx * 4);
                float zr[4] = {zv.x, zv.y, zv.z, zv.w};
                float er[8] = {ea.x, ea.y, ea.z, ea.w, eb.x, eb.y, eb.z, eb.w};
#pragma unroll
                for (int i = 0; i < 4; ++i)
#pragma unroll
                    for (int j = 0; j < 8; ++j)
                        acc[i][j] = fmaf(zr[i], er[j], acc[i][j]);
            }
        }

        // fold this k-tile into running argmin (k ascending; ties -> smaller k)
        float4 e2a = *(const float4*)(e2 + k0 + tx * 4);
        float4 e2b = *(const float4*)(e2 + k0 + 64 + tx * 4);
        float e2r[8] = {e2a.x, e2a.y, e2a.z, e2a.w, e2b.x, e2b.y, e2b.z, e2b.w};
#pragma unroll
        for (int i = 0; i < 4; ++i) {
#pragma unroll
            for (int j = 0; j < 8; ++j) {
                int k = k0 + (j < 4 ? tx * 4 + j : 64 + tx * 4 + (j - 4));
                float v = fmaf(-2.f, acc[i][j], e2r[j]);
                merge_min(v, k, bestv[i], besti[i]);
            }
        }
    }

    // cross-thread reduction: 16 tx candidates per pixel (alias et storage)
    float* redv = et;
    int*   redi = (int*)(et + TPX * 16);
    __syncthreads();
#pragma unroll
    for (int i = 0; i < 4; ++i) {
        int px = ty * 4 + i;
        redv[px * 16 + tx] = bestv[i];
        redi[px * 16 + tx] = besti[i];
    }
    __syncthreads();
    if (t < TPX) {
        float bv = redv[t * 16];
        int   bi = redi[t * 16];
#pragma unroll
        for (int j = 1; j < 16; ++j)
            merge_min(redv[t * 16 + j], redi[t * 16 + j], bv, bi);
        out_idx[n0 + t] = bi;
    }
}

// ---------------- kernel 3: gather codewords, write out, fused loss ----------------
__global__ void gather_kernel(const float* __restrict__ z,
                              const float* __restrict__ e,
                              const int* __restrict__ idx,
                              float* __restrict__ out,
                              float* __restrict__ loss) {
    const int t  = threadIdx.x;
    const int n0 = blockIdx.x * 64;
    __shared__ int kidx[64];
    if (t < 64) kidx[t] = idx[n0 + t];
    __syncthreads();

    const int p  = t & 63;   // pixel within tile (lane)
    const int d0 = t >> 6;   // wave id = d offset
    const size_t base = (size_t)(n0 >> 10) * (DD * HW) + (n0 & (HW - 1)) + p;
    const int kk = kidx[p];

    float acc = 0.f;
    for (int d = d0; d < DD; d += 4) {
        float ev = e[(size_t)d * KN + kk];     // gather (L2/L3-resident table)
        float zv = z[base + (size_t)d * HW];   // coalesced
        out[base + (size_t)d * HW] = zv + (ev - zv);  // straight-through value
        float df = ev - zv;
        acc = fmaf(df, df, acc);
    }

    // block reduction for loss
#pragma unroll
    for (int off = 32; off > 0; off >>= 1) acc += __shfl_down(acc, off, 64);
    __shared__ float part[4];
    if ((t & 63) == 0) part[t >> 6] = acc;
    __syncthreads();
    if (t == 0) {
        float s = (part[0] + part[1] + part[2] + part[3]) * (1.25f / 8388608.f);
        atomicAdd(loss, s);
    }
}

extern "C" void kernel_launch(void* const* d_in, const int* in_sizes, int n_in,
                              void* d_out, int out_size, void* d_ws, size_t ws_size,
                              hipStream_t stream) {
    const float* z = (const float*)d_in[0];   // [32,256,32,32]
    const float* e = (const float*)d_in[1];   // [256,8192]
    float* out  = (float*)d_out;
    float* loss = out + (size_t)NP * DD;      // element 8388608
    float* e2   = (float*)d_ws;               // 8192 floats
    int*   idx  = (int*)((char*)d_ws + KN * sizeof(float));  // 32768 ints

    hipMemsetAsync(loss, 0, sizeof(float), stream);  // d_out is 0xAA-poisoned pre-launch
    enorm_kernel<<<KN / 256, 256, 0, stream>>>(e, e2);
    argmin_kernel<<<NP / TPX, 256, 0, stream>>>(z, e, e2, idx);
    gather_kernel<<<NP / 64, 256, 0, stream>>>(z, e, idx, out, loss);
}

// Round 4
// 504.885 us; speedup vs baseline: 3.8232x; 3.8232x over previous
//
#include <hip/hip_runtime.h>

typedef unsigned int u32;
typedef unsigned short u16;
typedef __attribute__((ext_vector_type(8))) short bf16x8;  // 8 bf16 = 4 VGPRs
typedef __attribute__((ext_vector_type(4))) float f32x4;

#define KN 8192
#define DD 256
#define HW 1024
#define NP 32768
#define SPLITS 4
#define KSPLIT 2048
#define PXT 128
#define NTT 128

__device__ __forceinline__ u16 rne_bf16(float x) {
    u32 u = __float_as_uint(x);
    return (u16)((u + 0x7FFF + ((u >> 16) & 1)) >> 16);
}

__device__ __forceinline__ void glds16(const void* g, void* ldsbase) {
    __builtin_amdgcn_global_load_lds((const __attribute__((address_space(1))) u32*)g,
                                     (__attribute__((address_space(3))) u32*)ldsbase, 16, 0, 0);
}

// ---------------- e2f[k] = sum_d e[d,k]^2 (exact fp32) ----------------
__global__ void enorm_kernel(const float* __restrict__ e, float* __restrict__ e2f) {
    int k = blockIdx.x * blockDim.x + threadIdx.x;
    float acc = 0.f;
#pragma unroll 8
    for (int d = 0; d < DD; ++d) {
        float v = e[(size_t)d * KN + k];
        acc = fmaf(v, v, acc);
    }
    e2f[k] = acc;
}

// ------- eT[k][d] = bf16(e[d][k]);  eTf[k][d] = fp32 e[d][k] (for rescoring) -------
__global__ void prep_eT_kernel(const float* __restrict__ e, u16* __restrict__ eT,
                               float* __restrict__ eTf) {
    __shared__ float tt[64][65];
    const int t = threadIdx.x;
    const int kt = blockIdx.x;   // 0..127
    const int dt = blockIdx.y;   // 0..3
    const float* ep = e + (size_t)(dt * 64) * KN + kt * 64;
    {
        int k = t & 63, d0 = t >> 6;
#pragma unroll
        for (int j = 0; j < 16; ++j) tt[d0 + j * 4][k] = ep[(size_t)(d0 + j * 4) * KN + k];
    }
    __syncthreads();
    int k = t >> 2, c0 = (t & 3) * 16;
    u16 hi[16];
    float fv[16];
#pragma unroll
    for (int j = 0; j < 16; ++j) {
        float v = tt[c0 + j][k];
        fv[j] = v;
        hi[j] = rne_bf16(v);
    }
    u16* rowp = eT + (size_t)(kt * 64 + k) * 256 + dt * 64 + c0;
    *(uint4*)(rowp) = *(uint4*)(hi);
    *(uint4*)(rowp + 8) = *(uint4*)(hi + 8);
    float* rowpf = eTf + (size_t)(kt * 64 + k) * 256 + dt * 64 + c0;
#pragma unroll
    for (int j = 0; j < 4; ++j) *(float4*)(rowpf + j * 4) = *(float4*)(fv + j * 4);
}

// ---------------- A[n][d] = bf16(z[b,d,h,w]), n = b*1024 + h*32 + w ----------------
__global__ void prep_A_kernel(const float* __restrict__ z, u16* __restrict__ A) {
    __shared__ float tt[64][65];
    const int t = threadIdx.x;
    const int pt = blockIdx.x;   // 0..15
    const int dt = blockIdx.y;   // 0..3
    const int b  = blockIdx.z;   // 0..31
    const float* zp = z + (size_t)b * (DD * HW) + (size_t)(dt * 64) * HW + pt * 64;
    {
        int p = t & 63, d0 = t >> 6;
#pragma unroll
        for (int j = 0; j < 16; ++j) tt[d0 + j * 4][p] = zp[(size_t)(d0 + j * 4) * HW + p];
    }
    __syncthreads();
    int p = t >> 2, c0 = (t & 3) * 16;
    int n = b * HW + pt * 64 + p;
    u16 hi[16];
#pragma unroll
    for (int j = 0; j < 16; ++j) hi[j] = rne_bf16(tt[c0 + j][p]);
    u16* rowp = A + (size_t)n * 256 + dt * 64 + c0;
    *(uint4*)(rowp) = *(uint4*)(hi);
    *(uint4*)(rowp + 8) = *(uint4*)(hi + 8);
}

// ---------------- main: MFMA distance GEMM + streaming top-3 argmin ----------------
// Each wave owns 32 pixel-rows x ALL 128 codeword-cols of each n-tile, so its
// streaming top-3 spans the whole split; write-out rows are disjoint per wave.
__launch_bounds__(256, 3)
__global__ void argmin_mfma_kernel(const u16* __restrict__ A,   // [32768][256]
                                   const u16* __restrict__ eT,  // [8192][256]
                                   const float* __restrict__ e2f,
                                   int* __restrict__ keys) {    // [3][4][NP]
    __shared__ u16 Ast[PXT * 64];   // 16 KB, XOR-swizzled column slots
    __shared__ u16 Bst[NTT * 64];   // 16 KB

    const int t = threadIdx.x;
    const int w = t >> 6;
    const int l = t & 63;
    const int split = blockIdx.x & 3;
    const int pxt = blockIdx.x >> 2;
    const int px0 = pxt * PXT;
    const int kb0 = split * KSPLIT;

    const int swz  = (l & 7) ^ ((l >> 3) & 7);  // staging: fetch global slot swz
    const int srow = l >> 3;                    // row within 8-row group
    const int fr = l & 15;                      // frag row (m or n)
    const int g  = l >> 4;                      // quad -> k slice g*8..g*8+7

    int b1[8], b2[8], b3[8];
#pragma unroll
    for (int i = 0; i < 8; ++i) { b1[i] = 0x7FFFFFFF; b2[i] = 0x7FFFFFFF; b3[i] = 0x7FFFFFFF; }

    for (int nt = 0; nt < KSPLIT / NTT; ++nt) {
        const int n0 = kb0 + nt * NTT;
        f32x4 acc[2][8];
#pragma unroll
        for (int mi = 0; mi < 2; ++mi)
#pragma unroll
            for (int ni = 0; ni < 8; ++ni) acc[mi][ni] = (f32x4){0.f, 0.f, 0.f, 0.f};

        for (int kit = 0; kit < 4; ++kit) {
            __syncthreads();
#pragma unroll
            for (int i = 0; i < 4; ++i) {   // A: 128 rows x 64 bf16
                int r0 = w * 32 + i * 8;
                const u16* gp = A + (size_t)(px0 + r0 + srow) * 256 + kit * 64 + swz * 8;
                glds16(gp, &Ast[r0 * 64]);
            }
#pragma unroll
            for (int i = 0; i < 4; ++i) {   // B: 128 codewords x 64 bf16
                int r0 = w * 32 + i * 8;
                const u16* gp = eT + (size_t)(n0 + r0 + srow) * 256 + kit * 64 + swz * 8;
                glds16(gp, &Bst[r0 * 64]);
            }
            __syncthreads();
#pragma unroll
            for (int kc = 0; kc < 2; ++kc) {
                bf16x8 af[2], bfr[8];
#pragma unroll
                for (int mi = 0; mi < 2; ++mi) {
                    int row = w * 32 + mi * 16 + fr;
                    int slot = (kc * 4 + g) ^ (row & 7);
                    af[mi] = *(const bf16x8*)&Ast[row * 64 + slot * 8];
                }
#pragma unroll
                for (int ni = 0; ni < 8; ++ni) {
                    int row = ni * 16 + fr;
                    int slot = (kc * 4 + g) ^ (row & 7);
                    bfr[ni] = *(const bf16x8*)&Bst[row * 64 + slot * 8];
                }
#pragma unroll
                for (int mi = 0; mi < 2; ++mi)
#pragma unroll
                    for (int ni = 0; ni < 8; ++ni)
                        acc[mi][ni] = __builtin_amdgcn_mfma_f32_16x16x32_bf16(
                            af[mi], bfr[ni], acc[mi][ni], 0, 0, 0);
            }
        }

        // epilogue: key = trunc(256*(e2-2s))*8192 + k ; streaming top-3
#pragma unroll
        for (int ni = 0; ni < 8; ++ni) {
            int kcol = n0 + ni * 16 + fr;
            float e2c = e2f[kcol] * 256.f;
#pragma unroll
            for (int mi = 0; mi < 2; ++mi) {
#pragma unroll
                for (int r = 0; r < 4; ++r) {
                    float d = fmaf(acc[mi][ni][r], -512.f, e2c);
                    int key = (int)d * 8192 + kcol;
                    int i8 = mi * 4 + r;
                    int v1 = min(b1[i8], key);
                    int x  = max(b1[i8], key);
                    int v2 = min(b2[i8], x);
                    int y  = max(b2[i8], x);
                    int v3 = min(b3[i8], y);
                    b1[i8] = v1; b2[i8] = v2; b3[i8] = v3;
                }
            }
        }
    }

    // merge top-3 across the 16 fr-lanes (columns); g-groups hold distinct rows
#pragma unroll
    for (int m = 1; m < 16; m <<= 1) {
#pragma unroll
        for (int i = 0; i < 8; ++i) {
            int a1 = __shfl_xor(b1[i], m, 64);
            int a2 = __shfl_xor(b2[i], m, 64);
            int a3 = __shfl_xor(b3[i], m, 64);
            int m1 = min(b1[i], a1);
            int xx = max(b1[i], a1);
            int mn2 = min(b2[i], a2);
            int m2 = min(xx, mn2);
            int m3 = min(min(max(b2[i], a2), max(xx, mn2)), min(b3[i], a3));
            b1[i] = m1; b2[i] = m2; b3[i] = m3;
        }
    }
    if (fr == 0) {
        int* k1 = keys + split * NP;
        int* k2 = keys + (4 + split) * NP;
        int* k3 = keys + (8 + split) * NP;
#pragma unroll
        for (int mi = 0; mi < 2; ++mi)
#pragma unroll
            for (int r = 0; r < 4; ++r) {
                int row = px0 + w * 32 + mi * 16 + g * 4 + r;
                k1[row] = b1[mi * 4 + r];
                k2[row] = b2[mi * 4 + r];
                k3[row] = b3[mi * 4 + r];
            }
    }
}

// -------- combine: ALWAYS exact-rescore all 12 candidates in fp32 --------
__global__ void combine_kernel(const int* __restrict__ keys,
                               const float* __restrict__ z,
                               const float* __restrict__ eTf,
                               const float* __restrict__ e2f,
                               int* __restrict__ idx) {
    __shared__ float zt[DD * 65];     // padded: zt[d*65+p]
    const int t = threadIdx.x;
    const int n0 = blockIdx.x * 64;   // 64 pixels per block
    const float* zp = z + (size_t)(n0 >> 10) * (DD * HW) + (n0 & (HW - 1));
    for (int i = t; i < DD * 64; i += 256) {
        int d = i >> 6, p = i & 63;
        zt[d * 65 + p] = zp[(size_t)d * HW + p];   // coalesced
    }
    __syncthreads();

    const int l = t & 63, w = t >> 6;
    for (int q = 0; q < 16; ++q) {
        const int p = w * 16 + q;
        const int px = n0 + p;
        float zr0 = zt[(l      ) * 65 + p];
        float zr1 = zt[(l +  64) * 65 + p];
        float zr2 = zt[(l + 128) * 65 + p];
        float zr3 = zt[(l + 192) * 65 + p];
        float bv = 3.4e38f;
        int   bk = 0x7FFFFFFF;
#pragma unroll
        for (int c = 0; c < 12; ++c) {
            int k = keys[c * NP + px] & 8191;      // px wave-uniform -> scalar load
            const float* er = eTf + (size_t)k * 256;
            float acc = zr0 * er[l];
            acc = fmaf(zr1, er[l + 64], acc);
            acc = fmaf(zr2, er[l + 128], acc);
            acc = fmaf(zr3, er[l + 192], acc);
#pragma unroll
            for (int m = 1; m < 64; m <<= 1) acc += __shfl_xor(acc, m, 64);
            float d = fmaf(-2.f, acc, e2f[k]);     // exact fp32 (minus const ||z||^2)
            if (d < bv || (d == bv && k < bk)) { bv = d; bk = k; }
        }
        if (l == 0) idx[px] = bk;
    }
}

// ---------------- gather + fused loss (R1-proven) ----------------
__global__ void gather_kernel(const float* __restrict__ z,
                              const float* __restrict__ e,
                              const int* __restrict__ idx,
                              float* __restrict__ out,
                              float* __restrict__ loss) {
    const int t = threadIdx.x;
    const int n0 = blockIdx.x * 64;
    __shared__ int kidx[64];
    if (t < 64) kidx[t] = idx[n0 + t];
    __syncthreads();

    const int p = t & 63;
    const int d0 = t >> 6;
    const size_t base = (size_t)(n0 >> 10) * (DD * HW) + (n0 & (HW - 1)) + p;
    const int kk = kidx[p];

    float acc = 0.f;
    for (int d = d0; d < DD; d += 4) {
        float ev = e[(size_t)d * KN + kk];
        float zv = z[base + (size_t)d * HW];
        out[base + (size_t)d * HW] = zv + (ev - zv);
        float df = ev - zv;
        acc = fmaf(df, df, acc);
    }
#pragma unroll
    for (int off = 32; off > 0; off >>= 1) acc += __shfl_down(acc, off, 64);
    __shared__ float part[4];
    if ((t & 63) == 0) part[t >> 6] = acc;
    __syncthreads();
    if (t == 0) {
        float s = (part[0] + part[1] + part[2] + part[3]) * (1.25f / 8388608.f);
        atomicAdd(loss, s);
    }
}

extern "C" void kernel_launch(void* const* d_in, const int* in_sizes, int n_in,
                              void* d_out, int out_size, void* d_ws, size_t ws_size,
                              hipStream_t stream) {
    const float* z = (const float*)d_in[0];   // [32,256,32,32] fp32
    const float* e = (const float*)d_in[1];   // [256,8192] fp32
    float* out = (float*)d_out;
    float* loss = out + (size_t)NP * DD;      // element 8388608 (byte 32 MiB)

    // Large scratch lives inside d_out (33.55 MB), fully consumed before gather:
    char* ob = (char*)d_out;
    u16*   Acat = (u16*)ob;                          // [0, 16Mi)  bf16 z rows
    u16*   eT   = (u16*)(ob + ((size_t)16 << 20));   // [16Mi, 20Mi) bf16 e^T
    int*   keys = (int*)(ob + ((size_t)20 << 20));   // [20Mi, ~21.5Mi) 12 planes
    float* eTf  = (float*)(ob + ((size_t)23 << 20)); // [23Mi, 31Mi) fp32 e^T
    // d_ws: only 160 KB (R1-proven safe)
    float* e2f = (float*)d_ws;                       // 32 KB
    int*   idx = (int*)((char*)d_ws + 32768);        // 128 KB

    enorm_kernel<<<KN / 256, 256, 0, stream>>>(e, e2f);
    prep_eT_kernel<<<dim3(128, 4), 256, 0, stream>>>(e, eT, eTf);
    prep_A_kernel<<<dim3(16, 4, 32), 256, 0, stream>>>(z, Acat);
    argmin_mfma_kernel<<<SPLITS * (NP / PXT), 256, 0, stream>>>(Acat, eT, e2f, keys);
    combine_kernel<<<NP / 64, 256, 0, stream>>>(keys, z, eTf, e2f, idx);
    hipMemsetAsync(loss, 0, sizeof(float), stream);
    gather_kernel<<<NP / 64, 256, 0, stream>>>(z, e, idx, out, loss);
}